// Round 6
// baseline (58667.908 us; speedup 1.0000x reference)
//
#include <hip/hip_runtime.h>
#include <hip/hip_cooperative_groups.h>

namespace cg = cooperative_groups;

#define T_STEPS 256
#define B_SZ    128
#define S_SZ    512
#define D_SZ    256
#define NJ      1024   // 4*HID
#define KG      768    // emb(256) + ctx(256) + h(256)

// ---- static device scratch (ws_size-independent, graph-capture safe) ----
__device__ float g_projT[(size_t)B_SZ * D_SZ * S_SZ];   // 64 MiB  [b][d][s]
__device__ float g_tgtT [(size_t)T_STEPS * D_SZ * B_SZ];// 32 MiB  [t][e][b]
__device__ float g_Wg  [NJ * KG];                        // 3 MiB   [j][k]  k=emb|ctx|h
__device__ float g_WhT [D_SZ * D_SZ];                    // [u][d]
__device__ float g_WmT [D_SZ * D_SZ];                    // [e][d]
__device__ float g_bias[NJ];
__device__ float g_hT  [2][D_SZ * B_SZ];                 // [parity][u][b]
__device__ float g_ST  [2][2][D_SZ * B_SZ];              // [parity][half][e][b]
__device__ float g_mx  [2][2][B_SZ];                     // [parity][half][b]
__device__ float g_z   [2][2][B_SZ];

__device__ __forceinline__ float tanh_f(float x){
    float r = __expf(2.f * x);
    return 1.f - 2.f / (r + 1.f);
}
__device__ __forceinline__ float sigm_f(float x){
    return 1.f / (1.f + __expf(-x));
}

// ---- packing kernels ----
__global__ void pack_attn(const float* __restrict__ W_attn){
    int id = blockIdx.x * 256 + threadIdx.x;   // 65536
    int d = id >> 8, k = id & 255;
    g_WhT[k * 256 + d] = W_attn[d * 512 + k];
    g_WmT[k * 256 + d] = W_attn[d * 512 + 256 + k];
}
// combined gate weights: row j = [W_ih[j][0:512] | W_hh[j][0:256]]
__global__ void pack_gates(const float* __restrict__ W_ih, const float* __restrict__ W_hh){
    int id = blockIdx.x * 256 + threadIdx.x;   // 1024*768 = 786432
    int j = id / KG, k = id - j * KG;
    g_Wg[id] = (k < 512) ? W_ih[j * 512 + k] : W_hh[j * 256 + (k - 512)];
}
__global__ void pack_bias(const float* __restrict__ bih, const float* __restrict__ bhh){
    int j = blockIdx.x * 256 + threadIdx.x;    // 1024
    g_bias[j] = bih[j] + bhh[j];
}
// tgt [T][B][E] -> tgtT [T][E][B]
__global__ void transpose_tgt(const float* __restrict__ tgt){
    int id = blockIdx.x * 256 + threadIdx.x;   // 8388608
    int b = id & 127, e = (id >> 7) & 255, t = id >> 15;
    g_tgtT[id] = tgt[((size_t)t * B_SZ + b) * 256 + e];
}

// g_projT[b][d][s] = sum_e memory[s][b][e]*W_m[d][e] + b_attn[d]
#define PBM 64
#define PBN 64
#define PBK 32
__global__ __launch_bounds__(256) void mem_proj_gemm(
        const float* __restrict__ memory, const float* __restrict__ b_attn){
    __shared__ float As[PBK][PBM + 1];
    __shared__ float Bs[PBK][PBN + 1];
    int tid = threadIdx.x;
    int tm = tid >> 4, tn = tid & 15;
    int row0 = blockIdx.x * PBM;             // row r = b*512 + s
    int col0 = blockIdx.y * PBN;             // col = d
    float acc[4][4] = {};
    for (int k0 = 0; k0 < 256; k0 += PBK){
        int m = tid >> 2, kq = tid & 3;
        int r  = row0 + m;
        int bb = r >> 9, ss = r & 511;
        const float* ap = memory + ((size_t)ss * B_SZ + bb) * 256 + k0 + kq * 8;
        #pragma unroll
        for (int i = 0; i < 8; ++i) As[kq * 8 + i][m] = ap[i];
        int kk = tid >> 3, dq = tid & 7;
        const float* bp = g_WmT + (size_t)(k0 + kk) * 256 + col0 + dq * 8;
        #pragma unroll
        for (int i = 0; i < 8; ++i) Bs[kk][dq * 8 + i] = bp[i];
        __syncthreads();
        #pragma unroll
        for (int k2 = 0; k2 < PBK; ++k2){
            float a[4], bb2[4];
            #pragma unroll
            for (int i = 0; i < 4; ++i) a[i]   = As[k2][tm * 4 + i];
            #pragma unroll
            for (int i = 0; i < 4; ++i) bb2[i] = Bs[k2][tn * 4 + i];
            #pragma unroll
            for (int i = 0; i < 4; ++i)
                #pragma unroll
                for (int j = 0; j < 4; ++j) acc[i][j] += a[i] * bb2[j];
        }
        __syncthreads();
    }
    #pragma unroll
    for (int i = 0; i < 4; ++i){
        int r = row0 + tm * 4 + i;
        int bq = r >> 9, sq = r & 511;
        #pragma unroll
        for (int j = 0; j < 4; ++j){
            int d = col0 + tn * 4 + j;
            g_projT[((size_t)bq * 256 + d) * 512 + sq] = acc[i][j] + b_attn[d];
        }
    }
}

// ---- cooperative persistent scan: 256 blocks x 512 threads ----
__global__ __launch_bounds__(512) void decode_coop(
        const float* __restrict__ memory,    // [S][B][256]
        float* __restrict__ out)             // [T][B][256]
{
    cg::grid_group grid = cg::this_grid();
    const int u    = blockIdx.x;        // gate unit 0..255
    const int tid  = threadIdx.x;       // 0..511
    const int b_at = u >> 1;            // attention batch element
    const int half = u & 1;             // attention s-half
    const int s0   = half * 256;

    __shared__ float sWg[4][KG];        // 12 KB gate-weight rows (persistent)
    __shared__ float s_h[256];
    __shared__ float s_p2[2][256];
    __shared__ float s_hWh[256];
    __shared__ float s_e[256];
    __shared__ float s_attn[256];
    __shared__ float s_red[8];
    __shared__ float s_gate[4][128];

    // P2 role constants
    const int bb = tid & 127;
    const int jr = tid >> 7;                 // 0..3 -> gate i,f,g,o
    const float bias_r = g_bias[jr * 256 + u];
    float c_reg = 0.f;                       // cell state for (b=tid, u), tid<128

    // load persistent gate weights into LDS
    for (int idx = tid; idx < 4 * KG; idx += 512){
        int jr2 = idx / KG, kk = idx - jr2 * KG;
        sWg[jr2][kk] = g_Wg[(size_t)(jr2 * 256 + u) * KG + kk];
    }
    // init h parity-0, out[0]
    if (tid < 128){
        g_hT[0][u * 128 + tid] = 0.f;
        out[(size_t)tid * 256 + u] = 0.f;
    }
    __threadfence();
    grid.sync();

    for (int t = 1; t < T_STEPS; ++t){
        const int wb = t & 1, rb = wb ^ 1, sp = t & 1;

        // ================= P1: attention for (b_at, half) =================
        // load h[b_at][*]
        if (tid < 256) s_h[tid] = g_hT[rb][tid * 128 + b_at];
        __syncthreads();
        // hWh[d] = sum_u h[u] * W_hT[u][d]
        {
            int d = tid & 255, uh = tid >> 8;
            float acc = 0.f;
            const float* wp = g_WhT + (size_t)(uh * 128) * 256 + d;
            #pragma unroll 8
            for (int k = 0; k < 128; ++k)
                acc += s_h[uh * 128 + k] * wp[(size_t)k * 256];
            s_p2[uh][d] = acc;
        }
        __syncthreads();
        if (tid < 256) s_hWh[tid] = s_p2[0][tid] + s_p2[1][tid];
        __syncthreads();
        // energy: e[s] = sum_d tanh(projT[b][d][s] + hWh[d])
        {
            int sl = tid & 255, dh = tid >> 8;
            const float* pp = g_projT + ((size_t)b_at * 256 + dh * 128) * 512 + s0 + sl;
            float acc = 0.f;
            #pragma unroll 4
            for (int dd = 0; dd < 128; ++dd)
                acc += tanh_f(pp[(size_t)dd * 512] + s_hWh[dh * 128 + dd]);
            s_p2[dh][sl] = acc;
        }
        __syncthreads();
        if (tid < 256) s_e[tid] = s_p2[0][tid] + s_p2[1][tid];
        __syncthreads();
        // local softmax stats (max, expsum) over this 256-s half
        float mx, z;
        {
            float v = (tid < 256) ? s_e[tid] : -1e30f;
            #pragma unroll
            for (int m = 32; m; m >>= 1) v = fmaxf(v, __shfl_xor(v, m, 64));
            if ((tid & 63) == 0) s_red[tid >> 6] = v;
            __syncthreads();
            mx = fmaxf(fmaxf(s_red[0], s_red[1]), fmaxf(s_red[2], s_red[3]));
            __syncthreads();
            float p = (tid < 256) ? __expf(s_e[tid] - mx) : 0.f;
            if (tid < 256) s_attn[tid] = p;
            float zz = p;
            #pragma unroll
            for (int m = 32; m; m >>= 1) zz += __shfl_xor(zz, m, 64);
            if ((tid & 63) == 0) s_red[tid >> 6] = zz;
            __syncthreads();
            z = s_red[0] + s_red[1] + s_red[2] + s_red[3];
            if (tid == 0){ g_mx[sp][half][b_at] = mx; g_z[sp][half][b_at] = z; }
        }
        // partial (unnormalized) ctx: S[e] = sum_s p[s] * mem[s][b][e]
        {
            int e = tid & 255, sh2 = tid >> 8;
            const float* mp = memory + ((size_t)(s0 + sh2 * 128) * 128 + b_at) * 256 + e;
            float acc = 0.f;
            #pragma unroll 8
            for (int ss = 0; ss < 128; ++ss)
                acc += s_attn[sh2 * 128 + ss] * mp[(size_t)ss * 32768];
            s_p2[sh2][e] = acc;
        }
        __syncthreads();
        if (tid < 256)
            g_ST[sp][half][tid * 128 + b_at] = s_p2[0][tid] + s_p2[1][tid];
        __threadfence();
        grid.sync();

        // ================= P2: gates + cell for unit u, all b =================
        {
            float mx0 = g_mx[sp][0][bb], mx1 = g_mx[sp][1][bb];
            float z0  = g_z [sp][0][bb], z1  = g_z [sp][1][bb];
            float M   = fmaxf(mx0, mx1);
            float a0  = __expf(mx0 - M), a1 = __expf(mx1 - M);
            float inv = 1.f / (z0 * a0 + z1 * a1);
            float f0  = a0 * inv, f1 = a1 * inv;

            float acc = bias_r;
            const float* xt = g_tgtT + (size_t)t * 256 * 128 + bb;
            #pragma unroll 8
            for (int k = 0; k < 256; ++k)
                acc += sWg[jr][k] * xt[(size_t)k * 128];
            const float* S0 = g_ST[sp][0] + bb;
            const float* S1 = g_ST[sp][1] + bb;
            #pragma unroll 8
            for (int k = 0; k < 256; ++k)
                acc += sWg[jr][256 + k] * (f0 * S0[(size_t)k * 128] + f1 * S1[(size_t)k * 128]);
            const float* hp = g_hT[rb] + bb;
            #pragma unroll 8
            for (int k = 0; k < 256; ++k)
                acc += sWg[jr][512 + k] * hp[(size_t)k * 128];
            s_gate[jr][bb] = acc;
        }
        __syncthreads();
        if (tid < 128){
            float ig = sigm_f(s_gate[0][tid]);
            float fg = sigm_f(s_gate[1][tid]);
            float gg = tanh_f(s_gate[2][tid]);
            float og = sigm_f(s_gate[3][tid]);
            c_reg = fg * c_reg + ig * gg;
            float hn = og * tanh_f(c_reg);
            g_hT[wb][u * 128 + tid] = hn;
            out[((size_t)t * B_SZ + tid) * 256 + u] = hn;
        }
        __threadfence();
        grid.sync();
    }
}

extern "C" void kernel_launch(void* const* d_in, const int* in_sizes, int n_in,
                              void* d_out, int out_size, void* d_ws, size_t ws_size,
                              hipStream_t stream){
    const float* tgt    = (const float*)d_in[0];
    const float* memory = (const float*)d_in[1];
    const float* W_attn = (const float*)d_in[2];
    const float* b_attn = (const float*)d_in[3];
    const float* W_ih   = (const float*)d_in[4];
    const float* W_hh   = (const float*)d_in[5];
    const float* b_ih   = (const float*)d_in[6];
    const float* b_hh   = (const float*)d_in[7];
    float* out = (float*)d_out;
    (void)d_ws; (void)ws_size; (void)in_sizes; (void)n_in; (void)out_size;

    pack_attn<<<256, 256, 0, stream>>>(W_attn);
    pack_gates<<<3072, 256, 0, stream>>>(W_ih, W_hh);
    pack_bias<<<4, 256, 0, stream>>>(b_ih, b_hh);
    transpose_tgt<<<32768, 256, 0, stream>>>(tgt);
    mem_proj_gemm<<<dim3(1024, 4), 256, 0, stream>>>(memory, b_attn);

    void* args[] = { (void*)&memory, (void*)&out };
    hipLaunchCooperativeKernel((const void*)decode_coop, dim3(256), dim3(512),
                               args, 0, stream);
}